// Round 4
// baseline (1184.104 us; speedup 1.0000x reference)
//
#include <hip/hip_runtime.h>
#include <stdint.h>

typedef __attribute__((ext_vector_type(8))) short short8;
typedef __attribute__((ext_vector_type(4))) short s16x4;
typedef __attribute__((ext_vector_type(4))) float f32x4;
typedef __attribute__((ext_vector_type(4))) uint32_t uint32x4;

#define RES 56
#define NCH 256
#define SW 392     // valid tokens per window (56*7)
#define SP 424     // V^T token pitch in shorts (212 dwords, 212%32==20 -> conflict-free reads)
#define TSH 8      // +8 token shift: slot = tok + 8, slots 0..7 zeroed

// LDS layout (bytes), total 54016 -> 3 blocks/CU (3*54272 <= 160KB)
#define KP_OFF   0        // K panels: 4 x [400][8 shorts] = 25600 B
#define VT_OFF   25600    // V^T bf16 [d(32)][slot(424)] = 27136 B
#define WB_OFF   52736    // conv w [9][32] f32 = 1152 B
#define BB_OFF   53888    // bias [32] f32 = 128 B
#define SMEM_SZ  54016

__device__ __forceinline__ uint32_t cvtpk(float lo, float hi) {   // RNE pack
    uint32_t r;
    asm("v_cvt_pk_bf16_f32 %0, %1, %2" : "=v"(r) : "v"(lo), "v"(hi));
    return r;
}

__global__ __launch_bounds__(256, 3) void lepe_attn_kernel(
    const float* __restrict__ qg, const float* __restrict__ kg,
    const float* __restrict__ vg, const float* __restrict__ wg,
    const float* __restrict__ bg, float* __restrict__ outg)
{
    __shared__ __align__(16) char smem[SMEM_SZ];
    short* kpan = (short*)(smem + KP_OFF);
    short* vtb  = (short*)(smem + VT_OFF);
    float* wbuf = (float*)(smem + WB_OFF);
    float* bbuf = (float*)(smem + BB_OFF);

    const int tid  = threadIdx.x;
    const int lane = tid & 63;
    const int wv   = tid >> 6;
    const int col  = lane & 15;   // MFMA n/m index
    const int g    = lane >> 4;   // MFMA quad

    const int h  = blockIdx.x & 7;        // head
    const int bw = blockIdx.x >> 3;       // window id
    const int s  = bw & 7;                // stripe index
    const int b  = bw >> 3;               // batch

    const int cb = h * 32;                // channel base
    const int tb = b * (RES * RES);       // token base

    // ---- stage conv weights + bias ----
    for (int i = tid; i < 288; i += 256)
        wbuf[i] = wg[(i >> 5) * NCH + cb + (i & 31)];
    if (tid < 32)
        bbuf[tid] = bg[cb + tid];

    // ---- zero pad slots 0..7 of every V^T row ----
    vtb[(tid >> 3) * SP + (tid & 7)] = 0;

    // ---- stage K (panel-major) and V^T as bf16; wave-uniform hd8 ----
    {
        const int hd8 = wv << 3;
        #pragma unroll
        for (int it = 0; it < 7; ++it) {
            int tok = (it << 6) + lane;
            if (tok < 416) {
                f32x4 ka = {0.f,0.f,0.f,0.f}, kb2 = ka, va = ka, vb = ka;
                if (tok < SW) {
                    int y  = (tok * 9363) >> 16;    // tok/7 exact for tok<1871
                    int xx = tok - y * 7;
                    int n  = y * RES + s * 7 + xx;
                    int off = (tb + n) * NCH + cb + hd8;
                    ka  = *(const f32x4*)(kg + off);
                    kb2 = *(const f32x4*)(kg + off + 4);
                    va  = *(const f32x4*)(vg + off);
                    vb  = *(const f32x4*)(vg + off + 4);
                }
                if (tok < 400) {
                    uint32x4 kv;
                    kv[0] = cvtpk(ka[0],  ka[1]);
                    kv[1] = cvtpk(ka[2],  ka[3]);
                    kv[2] = cvtpk(kb2[0], kb2[1]);
                    kv[3] = cvtpk(kb2[2], kb2[3]);
                    *(uint32x4*)(kpan + wv * 3200 + tok * 8) = kv;  // b128, bank-balanced
                }
                uint32_t v01 = cvtpk(va[0], va[1]);
                uint32_t v23 = cvtpk(va[2], va[3]);
                uint32_t v45 = cvtpk(vb[0], vb[1]);
                uint32_t v67 = cvtpk(vb[2], vb[3]);
                short* vr = vtb + hd8 * SP + tok + TSH;   // 64 consecutive slots per wave
                vr[0]      = (short)v01;
                vr[SP]     = (short)(v01 >> 16);
                vr[2*SP]   = (short)v23;
                vr[3*SP]   = (short)(v23 >> 16);
                vr[4*SP]   = (short)v45;
                vr[5*SP]   = (short)(v45 >> 16);
                vr[6*SP]   = (short)v67;
                vr[7*SP]   = (short)(v67 >> 16);
            }
        }
    }
    __syncthreads();

    const float SCL = 0.17677669529663688f * 1.4426950408889634f; // hd^-0.5 * log2(e)
    const f32x4 zero4 = {0.f, 0.f, 0.f, 0.f};
    const short* kg0 = kpan + g * 3200 + col * 8;

    s16x4 ones;                                     // bf16 1.0 x4, A-operand for l-sum MFMA
    ones[0] = ones[1] = ones[2] = ones[3] = (short)0x3F80;

    // LePE lane constants: window parities depend only on col
    const uint32_t SEL = 0x05040000u;               // take src.lo16 -> result hi16
    const uint32_t pc0 = (col & 1) ? 0x02020000u : 0u;   // windows 0,2 parity
    const uint32_t pc1 = pc0 ^ 0x02020000u;              // window 1 parity (ofs 7)
    const bool p0o = (col & 1) != 0;
    const bool p1o = !p0o;

    // ---- Q prefetch prologue ----
    f32x4 qa, qb; int nq;
    {
        int qrow0 = (wv << 4) + col;
        int tq = qrow0 < SW ? qrow0 : SW - 1;
        int yq = (tq * 9363) >> 16;
        nq = yq * RES + s * 7 + (tq - yq * 7);
        const float* qp = qg + (size_t)(tb + nq) * NCH + cb + (g << 3);
        qa = *(const f32x4*)qp;
        qb = *(const f32x4*)(qp + 4);
    }

    for (int qt = wv; qt < 25; qt += 4) {
        int qrow = (qt << 4) + col;
        int nq_cur = nq;
        short8 qf;
        {
            union { uint32_t u[4]; short8 s8; } qu;
            qu.u[0] = cvtpk(qa[0]*SCL, qa[1]*SCL);
            qu.u[1] = cvtpk(qa[2]*SCL, qa[3]*SCL);
            qu.u[2] = cvtpk(qb[0]*SCL, qb[1]*SCL);
            qu.u[3] = cvtpk(qb[2]*SCL, qb[3]*SCL);
            qf = qu.s8;
        }
        // prefetch next tile's Q (hides under QK/PV/LePE)
        {
            int qrow2 = qrow + 64;
            int tq = qrow2 < SW ? qrow2 : SW - 1;
            int yq = (tq * 9363) >> 16;
            nq = yq * RES + s * 7 + (tq - yq * 7);
            const float* qp = qg + (size_t)(tb + nq) * NCH + cb + (g << 3);
            qa = *(const f32x4*)qp;
            qb = *(const f32x4*)(qp + 4);
        }

        // ---- QK^T + exp2 + pack fused (no max subtraction: shift-invariant) ----
        uint32_t pkk[25][2];
        #pragma unroll
        for (int kt = 0; kt < 25; ++kt) {
            short8 kf = *(const short8*)(kg0 + kt * 128);
            f32x4 Sv = __builtin_amdgcn_mfma_f32_16x16x32_bf16(kf, qf, zero4, 0, 0, 0);
            float p0 = exp2f(Sv[0]);
            float p1 = exp2f(Sv[1]);
            float p2 = exp2f(Sv[2]);
            float p3 = exp2f(Sv[3]);
            if (kt == 24 && g >= 2) { p0 = 0.f; p1 = 0.f; p2 = 0.f; p3 = 0.f; } // toks 392..399
            pkk[kt][0] = __builtin_amdgcn_perm(__float_as_uint(p1), __float_as_uint(p0), 0x07060302u);
            pkk[kt][1] = __builtin_amdgcn_perm(__float_as_uint(p3), __float_as_uint(p2), 0x07060302u);
        }

        // ---- O^T = V^T * P^T via 16x16x16 MFMA; l via ones-MFMA ----
        f32x4 O0a = zero4, O0b = zero4, O1a = zero4, O1b = zero4, lac = zero4;
        const short* va0 = vtb + col * SP + TSH + (g << 2);   // d = col
        const short* va1 = va0 + 16 * SP;                     // d = col+16
        #pragma unroll
        for (int kt = 0; kt < 25; ++kt) {
            s16x4 a0 = *(const s16x4*)(va0 + (kt << 4));
            s16x4 a1 = *(const s16x4*)(va1 + (kt << 4));
            union { uint32_t u[2]; s16x4 s4; } pu;
            pu.u[0] = pkk[kt][0]; pu.u[1] = pkk[kt][1];
            lac = __builtin_amdgcn_mfma_f32_16x16x16bf16_1k(ones, pu.s4, lac, 0, 0, 0);
            if (kt & 1) {
                O0b = __builtin_amdgcn_mfma_f32_16x16x16bf16_1k(a0, pu.s4, O0b, 0, 0, 0);
                O1b = __builtin_amdgcn_mfma_f32_16x16x16bf16_1k(a1, pu.s4, O1b, 0, 0, 0);
            } else {
                O0a = __builtin_amdgcn_mfma_f32_16x16x16bf16_1k(a0, pu.s4, O0a, 0, 0, 0);
                O1a = __builtin_amdgcn_mfma_f32_16x16x16bf16_1k(a1, pu.s4, O1a, 0, 0, 0);
            }
        }
        float invl = __builtin_amdgcn_rcpf(lac[0]);

        // ---- LePE in output layout: lane (g,col) computes channels 4g+r, 16+4g+r ----
        // tap slots: top = qrow..qrow+2, mid = +7..+9, bot = +14..+16 (TSH-folded)
        int xx = qrow - ((qrow * 9363) >> 16) * 7;
        float mlft = (xx == 0) ? 0.f : 1.f;
        float mrgt = (xx == 6) ? 0.f : 1.f;
        const volatile float* vw  = wbuf;   // volatile: prevent hoisting 80 loads into VGPRs
        const volatile float* vbb = bbuf;
        f32x4 r0, r1;
        #pragma unroll
        for (int r = 0; r < 4; ++r) {
            float oo0, oo1;
            #pragma unroll
            for (int hh = 0; hh < 2; ++hh) {
                int d = (hh << 4) + (g << 2) + r;
                const short* vrow = vtb + d * SP;
                int b0 = qrow & ~1;
                uint32_t A0 = *(const uint32_t*)(vrow + b0);
                uint32_t B0 = *(const uint32_t*)(vrow + b0 + 2);
                int b1 = (qrow + 7) & ~1;
                uint32_t A1 = *(const uint32_t*)(vrow + b1);
                uint32_t B1 = *(const uint32_t*)(vrow + b1 + 2);
                int b2 = (qrow + 14) & ~1;
                uint32_t A2 = *(const uint32_t*)(vrow + b2);
                uint32_t B2 = *(const uint32_t*)(vrow + b2 + 2);
                // parity-based tap extraction (bf16 -> f32 via high-half placement)
                float tA0 = __uint_as_float(__builtin_amdgcn_perm(A0, 0u, SEL + pc0));
                float tB0 = __uint_as_float(__builtin_amdgcn_perm(p0o ? B0 : A0, 0u, SEL + pc1));
                float tC0 = __uint_as_float(__builtin_amdgcn_perm(B0, 0u, SEL + pc0));
                float tA1 = __uint_as_float(__builtin_amdgcn_perm(A1, 0u, SEL + pc1));
                float tB1 = __uint_as_float(__builtin_amdgcn_perm(p1o ? B1 : A1, 0u, SEL + pc0));
                float tC1 = __uint_as_float(__builtin_amdgcn_perm(B1, 0u, SEL + pc1));
                float tA2 = __uint_as_float(__builtin_amdgcn_perm(A2, 0u, SEL + pc0));
                float tB2 = __uint_as_float(__builtin_amdgcn_perm(p0o ? B2 : A2, 0u, SEL + pc1));
                float tC2 = __uint_as_float(__builtin_amdgcn_perm(B2, 0u, SEL + pc0));
                // weight reads: same-address broadcast within each 16-lane group
                float L  = tA0 * vw[d]      + tA1 * vw[96 + d]  + tA2 * vw[192 + d];
                float Cc = tB0 * vw[32 + d] + tB1 * vw[128 + d] + tB2 * vw[224 + d];
                float Rr = tC0 * vw[64 + d] + tC1 * vw[160 + d] + tC2 * vw[256 + d];
                float o  = fmaf(L, mlft, fmaf(Rr, mrgt, Cc + vbb[d]));
                if (hh == 0) oo0 = o; else oo1 = o;
            }
            r0[r] = (O0a[r] + O0b[r]) * invl + oo0;
            r1[r] = (O1a[r] + O1b[r]) * invl + oo1;
        }

        if (qrow < SW) {
            float* op = outg + (size_t)(tb + nq_cur) * NCH + cb + (g << 2);
            *(f32x4*)op = r0;
            *(f32x4*)(op + 16) = r1;
        }
    }
}

extern "C" void kernel_launch(void* const* d_in, const int* in_sizes, int n_in,
                              void* d_out, int out_size, void* d_ws, size_t ws_size,
                              hipStream_t stream) {
    const float* q  = (const float*)d_in[0];
    const float* k  = (const float*)d_in[1];
    const float* v  = (const float*)d_in[2];
    const float* wc = (const float*)d_in[3];
    const float* bc = (const float*)d_in[4];
    float* out = (float*)d_out;
    hipLaunchKernelGGL(lepe_attn_kernel, dim3(2048), dim3(256), 0, stream,
                       q, k, v, wc, bc, out);
}